// Round 1
// baseline (635.812 us; speedup 1.0000x reference)
//
#include <hip/hip_runtime.h>
#include <math.h>

#define TOKENS 16384
#define C 1024
#define RH 256     // router hidden
#define E 32
#define D 32       // per-expert block dim
#define H 128      // expert hidden
#define BM 128
#define BN 64
#define BK 32

// ---------------- Kernel 1: ternary quantize + transpose ----------------
// blockIdx 0: gate [E][H][D] -> gT [E][D][H]
// blockIdx 1: up   [E][H][D] -> uT [E][D][H]
// blockIdx 2: down [E][D][H] -> dT [E][H][D]
__global__ __launch_bounds__(256) void quant_kernel(
    const float* __restrict__ gate, const float* __restrict__ up,
    const float* __restrict__ down, float* __restrict__ gT,
    float* __restrict__ uT, float* __restrict__ dT) {
    const int which = blockIdx.x;
    const float* src = which == 0 ? gate : (which == 1 ? up : down);
    float* dst = which == 0 ? gT : (which == 1 ? uT : dT);
    const int Nel = E * H * D; // 131072
    const int tid = threadIdx.x;
    double s = 0.0;
    for (int i = tid; i < Nel; i += 256) s += (double)fabsf(src[i]);
    __shared__ double red[256];
    red[tid] = s;
    __syncthreads();
    for (int off = 128; off > 0; off >>= 1) {
        if (tid < off) red[tid] += red[tid + off];
        __syncthreads();
    }
    const float gamma = (float)(red[0] / (double)Nel) + 1e-8f;
    for (int i = tid; i < Nel; i += 256) {
        float q = rintf(src[i] / gamma);            // round-half-even, matches jnp.round
        q = fminf(1.f, fmaxf(-1.f, q)) * gamma;
        const int e = i >> 12, r = i & 4095;
        int o;
        if (which < 2) { const int h = r >> 5, d = r & 31;  o = (e << 12) + (d << 7) + h; }
        else           { const int d = r >> 7, h = r & 127; o = (e << 12) + (h << 5) + d; }
        dst[o] = q;
    }
}

// ---------------- Kernel 2: H1 = silu(X @ W1^T), fp32 tiled GEMM ----------------
// X [16384,1024] row-major, W1 [256,1024] row-major (i.e. B^T layout), H1 [16384,256]
__global__ __launch_bounds__(256) void gemm1_silu(
    const float* __restrict__ X, const float* __restrict__ W1,
    float* __restrict__ H1) {
    __shared__ float As[BK][BM + 4];   // k-major, pad 4 keeps 16B alignment, breaks bank stride
    __shared__ float Bs[BK][BN + 4];
    const int tid = threadIdx.x;
    const int row0 = blockIdx.x * BM;
    const int col0 = blockIdx.y * BN;
    const int tx = tid & 15;           // 4 cols each
    const int ty = tid >> 4;           // 8 rows each
    float acc[8][4] = {};
    for (int kt = 0; kt < C; kt += BK) {
        #pragma unroll
        for (int L = 0; L < 4; ++L) {      // A tile: 128x32 floats = 1024 float4
            const int f = tid + L * 256;
            const int r = f >> 3, kq = (f & 7) << 2;
            const float4 v = *(const float4*)&X[(long)(row0 + r) * C + kt + kq];
            As[kq + 0][r] = v.x; As[kq + 1][r] = v.y;
            As[kq + 2][r] = v.z; As[kq + 3][r] = v.w;
        }
        #pragma unroll
        for (int L = 0; L < 2; ++L) {      // B tile: 64x32 floats = 512 float4
            const int f = tid + L * 256;
            const int n = f >> 3, kq = (f & 7) << 2;
            const float4 v = *(const float4*)&W1[(long)(col0 + n) * C + kt + kq];
            Bs[kq + 0][n] = v.x; Bs[kq + 1][n] = v.y;
            Bs[kq + 2][n] = v.z; Bs[kq + 3][n] = v.w;
        }
        __syncthreads();
        #pragma unroll
        for (int kk = 0; kk < BK; ++kk) {
            const float4 a0 = *(const float4*)&As[kk][ty * 8];
            const float4 a1 = *(const float4*)&As[kk][ty * 8 + 4];
            const float4 b  = *(const float4*)&Bs[kk][tx * 4];
            const float av[8] = {a0.x, a0.y, a0.z, a0.w, a1.x, a1.y, a1.z, a1.w};
            const float bv[4] = {b.x, b.y, b.z, b.w};
            #pragma unroll
            for (int i = 0; i < 8; ++i)
                #pragma unroll
                for (int j = 0; j < 4; ++j)
                    acc[i][j] = fmaf(av[i], bv[j], acc[i][j]);
        }
        __syncthreads();
    }
    #pragma unroll
    for (int i = 0; i < 8; ++i) {
        const int r = row0 + ty * 8 + i;
        float4 o;
        float* po = &o.x;
        #pragma unroll
        for (int j = 0; j < 4; ++j) {
            const float v = acc[i][j];
            po[j] = v / (1.f + __expf(-v));          // silu
        }
        *(float4*)&H1[(long)r * RH + col0 + tx * 4] = o;
    }
}

// ---------------- Kernel 3: logits = H1 @ W2^T, top-4, weights ----------------
// one thread per token; W2 [32][256] staged transposed in LDS
__global__ __launch_bounds__(64) void router2_kernel(
    const float* __restrict__ H1, const float* __restrict__ W2,
    int* __restrict__ rid, float* __restrict__ rw) {
    __shared__ float w2s[RH][E + 1];   // [h][e], +1 pad breaks write-bank aliasing
    const int tid = threadIdx.x;
    for (int i = tid; i < E * RH; i += 64) {
        const int e = i >> 8, h = i & 255;
        w2s[h][e] = W2[i];
    }
    __syncthreads();
    const int tok = blockIdx.x * 64 + tid;
    float l[E] = {};
    const float* hp = H1 + (long)tok * RH;
    for (int h = 0; h < RH; h += 4) {
        const float4 xv = *(const float4*)&hp[h];
        const float xs[4] = {xv.x, xv.y, xv.z, xv.w};
        #pragma unroll
        for (int q = 0; q < 4; ++q)
            #pragma unroll
            for (int e = 0; e < E; ++e)
                l[e] = fmaf(xs[q], w2s[h + q][e], l[e]);
    }
    // top-4 (ties -> lowest index, matches jax.lax.top_k)
    unsigned chosen = 0u;
    float tv[4]; int ti[4];
    #pragma unroll
    for (int s = 0; s < 4; ++s) {
        float best = -1e30f; int bi = 0;
        #pragma unroll
        for (int e = 0; e < E; ++e) {
            const bool ok = (((chosen >> e) & 1u) == 0u) && (l[e] > best);
            best = ok ? l[e] : best;
            bi   = ok ? e    : bi;
        }
        chosen |= 1u << bi;
        tv[s] = best; ti[s] = bi;
    }
    // softmax denominator cancels under top-4 renormalization
    const float m = tv[0];
    const float e0 = __expf(tv[0] - m), e1 = __expf(tv[1] - m);
    const float e2 = __expf(tv[2] - m), e3 = __expf(tv[3] - m);
    const float inv = 1.f / (e0 + e1 + e2 + e3);
    rid[tok * 4 + 0] = ti[0]; rw[tok * 4 + 0] = e0 * inv;
    rid[tok * 4 + 1] = ti[1]; rw[tok * 4 + 1] = e1 * inv;
    rid[tok * 4 + 2] = ti[2]; rw[tok * 4 + 2] = e2 * inv;
    rid[tok * 4 + 3] = ti[3]; rw[tok * 4 + 3] = e3 * inv;
}

// ---------------- Kernel 4: zero output (unselected blocks must be 0) ----------------
__global__ void zero_kernel(float4* __restrict__ out, int n4) {
    int i = blockIdx.x * blockDim.x + threadIdx.x;
    const int stride = gridDim.x * blockDim.x;
    for (; i < n4; i += stride) out[i] = make_float4(0.f, 0.f, 0.f, 0.f);
}

// ---------------- Kernel 5: experts — one wave per (token, top-k slot) ----------------
__global__ __launch_bounds__(256) void expert_kernel(
    const float* __restrict__ X, const float* __restrict__ gT,
    const float* __restrict__ uT, const float* __restrict__ dT,
    const int* __restrict__ rid, const float* __restrict__ rw,
    float* __restrict__ out) {
    __shared__ float hids[4][H];
    const int tok  = blockIdx.x;
    const int tid  = threadIdx.x;
    const int s    = tid >> 6;     // wave = top-k slot
    const int lane = tid & 63;
    const int e    = rid[tok * 4 + s];
    const float wt = rw[tok * 4 + s];
    const float* xb = X + (long)tok * C + e * D;
    float xv[D];
    #pragma unroll
    for (int d = 0; d < D; ++d) xv[d] = xb[d];   // wave-uniform broadcast loads
    const float* gp = gT + (e << 12);
    const float* up = uT + (e << 12);
    float g0 = 0.f, g1 = 0.f, u0 = 0.f, u1 = 0.f;
    #pragma unroll
    for (int d = 0; d < D; ++d) {                // coalesced: lanes read consecutive h
        g0 = fmaf(xv[d], gp[d * H + lane],      g0);
        g1 = fmaf(xv[d], gp[d * H + 64 + lane], g1);
        u0 = fmaf(xv[d], up[d * H + lane],      u0);
        u1 = fmaf(xv[d], up[d * H + 64 + lane], u1);
    }
    hids[s][lane]      = g0 / (1.f + __expf(-g0)) * u0;
    hids[s][lane + 64] = g1 / (1.f + __expf(-g1)) * u1;
    __syncthreads();
    if (lane < D) {
        const float* dp = dT + (e << 12);
        float acc = 0.f;
        #pragma unroll
        for (int h = 0; h < H; ++h)              // hids broadcast; dp coalesced over d
            acc = fmaf(hids[s][h], dp[h * D + lane], acc);
        out[(long)tok * C + e * D + lane] = wt * acc;
    }
}

extern "C" void kernel_launch(void* const* d_in, const int* in_sizes, int n_in,
                              void* d_out, int out_size, void* d_ws, size_t ws_size,
                              hipStream_t stream) {
    const float* x  = (const float*)d_in[0];
    const float* w1 = (const float*)d_in[1];
    const float* w2 = (const float*)d_in[2];
    const float* gw = (const float*)d_in[3];
    const float* uw = (const float*)d_in[4];
    const float* dw = (const float*)d_in[5];
    float* out = (float*)d_out;

    char* ws = (char*)d_ws;
    float* gT  = (float*)(ws);                                  // 512 KB
    float* uT  = (float*)(ws + (512 << 10));                    // 512 KB
    float* dT  = (float*)(ws + (1024 << 10));                   // 512 KB
    float* H1  = (float*)(ws + (1536 << 10));                   // 16 MB
    int*   rid = (int*)  (ws + (1536 << 10) + (16 << 20));      // 256 KB
    float* rw  = (float*)(ws + (1536 << 10) + (16 << 20) + (256 << 10));

    quant_kernel<<<3, 256, 0, stream>>>(gw, uw, dw, gT, uT, dT);
    dim3 g1(TOKENS / BM, RH / BN);
    gemm1_silu<<<g1, 256, 0, stream>>>(x, w1, H1);
    router2_kernel<<<TOKENS / 64, 64, 0, stream>>>(H1, w2, rid, rw);
    zero_kernel<<<4096, 256, 0, stream>>>((float4*)out, TOKENS * C / 4);
    expert_kernel<<<TOKENS, 256, 0, stream>>>(x, gT, uT, dT, rid, rw, out);
}

// Round 2
// 387.710 us; speedup vs baseline: 1.6399x; 1.6399x over previous
//
#include <hip/hip_runtime.h>
#include <math.h>

#define TOKENS 16384
#define C 1024
#define RH 256     // router hidden
#define E 32
#define D 32       // per-expert block dim
#define H 128      // expert hidden
#define BM 128
#define BN 64
#define BK 32
#define NEL (E * H * D)   // 131072 elements per weight tensor

// ---------------- Kernel 1a: partial |w| sums (deterministic per-block) ----------------
// grid (32, 3): blockIdx.y = which matrix, blockIdx.x = chunk. 4096 elems/block.
__global__ __launch_bounds__(256) void absum_kernel(
    const float* __restrict__ gate, const float* __restrict__ up,
    const float* __restrict__ down, double* __restrict__ partial) {
    const int which = blockIdx.y;
    const float* src = which == 0 ? gate : (which == 1 ? up : down);
    const float4* src4 = (const float4*)src;
    const int base4 = blockIdx.x * 1024;      // 1024 float4 per chunk
    const int tid = threadIdx.x;
    double s = 0.0;
    #pragma unroll
    for (int v = 0; v < 4; ++v) {
        const float4 f = src4[base4 + tid + v * 256];
        s += (double)fabsf(f.x) + (double)fabsf(f.y) +
             (double)fabsf(f.z) + (double)fabsf(f.w);
    }
    __shared__ double red[256];
    red[tid] = s;
    __syncthreads();
    for (int off = 128; off > 0; off >>= 1) {
        if (tid < off) red[tid] += red[tid + off];
        __syncthreads();
    }
    if (tid == 0) partial[which * 32 + blockIdx.x] = red[0];
}

// ---------------- Kernel 1b: fold partials -> gamma[3] ----------------
__global__ void gamma_kernel(const double* __restrict__ partial,
                             float* __restrict__ gammaArr) {
    const int t = threadIdx.x;
    if (t < 3) {
        double s = 0.0;
        for (int j = 0; j < 32; ++j) s += partial[t * 32 + j];
        gammaArr[t] = (float)(s / (double)NEL) + 1e-8f;   // same math as passing r1
    }
}

// ---------------- Kernel 1c: elementwise quantize + transpose ----------------
// gate [E][H][D] -> gT [E][D][H];  up likewise;  down [E][D][H] -> dT [E][H][D]
__global__ __launch_bounds__(256) void quant_t_kernel(
    const float* __restrict__ gate, const float* __restrict__ up,
    const float* __restrict__ down, const float* __restrict__ gammaArr,
    float* __restrict__ gT, float* __restrict__ uT, float* __restrict__ dT) {
    const int idx = blockIdx.x * 256 + threadIdx.x;   // [0, 3*131072)
    const int which = idx >> 17;
    const int i = idx & (NEL - 1);
    const float* src = which == 0 ? gate : (which == 1 ? up : down);
    float* dst = which == 0 ? gT : (which == 1 ? uT : dT);
    const float gamma = gammaArr[which];
    float q = rintf(src[i] / gamma);                  // round-half-even = jnp.round
    q = fminf(1.f, fmaxf(-1.f, q)) * gamma;
    const int e = i >> 12, r = i & 4095;
    int o;
    if (which < 2) { const int h = r >> 5, d = r & 31;  o = (e << 12) + (d << 7) + h; }
    else           { const int d = r >> 7, h = r & 127; o = (e << 12) + (h << 5) + d; }
    dst[o] = q;
}

// ---------------- Kernel 2: H1 = silu(X @ W1^T), fp32 tiled GEMM ----------------
__global__ __launch_bounds__(256) void gemm1_silu(
    const float* __restrict__ X, const float* __restrict__ W1,
    float* __restrict__ H1) {
    __shared__ float As[BK][BM + 4];
    __shared__ float Bs[BK][BN + 4];
    const int tid = threadIdx.x;
    const int row0 = blockIdx.x * BM;
    const int col0 = blockIdx.y * BN;
    const int tx = tid & 15;           // 4 cols each
    const int ty = tid >> 4;           // 8 rows each
    float acc[8][4] = {};
    for (int kt = 0; kt < C; kt += BK) {
        #pragma unroll
        for (int L = 0; L < 4; ++L) {      // A tile: 128x32
            const int f = tid + L * 256;
            const int r = f >> 3, kq = (f & 7) << 2;
            const float4 v = *(const float4*)&X[(long)(row0 + r) * C + kt + kq];
            As[kq + 0][r] = v.x; As[kq + 1][r] = v.y;
            As[kq + 2][r] = v.z; As[kq + 3][r] = v.w;
        }
        #pragma unroll
        for (int L = 0; L < 2; ++L) {      // B tile: 64x32
            const int f = tid + L * 256;
            const int n = f >> 3, kq = (f & 7) << 2;
            const float4 v = *(const float4*)&W1[(long)(col0 + n) * C + kt + kq];
            Bs[kq + 0][n] = v.x; Bs[kq + 1][n] = v.y;
            Bs[kq + 2][n] = v.z; Bs[kq + 3][n] = v.w;
        }
        __syncthreads();
        #pragma unroll
        for (int kk = 0; kk < BK; ++kk) {
            const float4 a0 = *(const float4*)&As[kk][ty * 8];
            const float4 a1 = *(const float4*)&As[kk][ty * 8 + 4];
            const float4 b  = *(const float4*)&Bs[kk][tx * 4];
            const float av[8] = {a0.x, a0.y, a0.z, a0.w, a1.x, a1.y, a1.z, a1.w};
            const float bv[4] = {b.x, b.y, b.z, b.w};
            #pragma unroll
            for (int i = 0; i < 8; ++i)
                #pragma unroll
                for (int j = 0; j < 4; ++j)
                    acc[i][j] = fmaf(av[i], bv[j], acc[i][j]);
        }
        __syncthreads();
    }
    #pragma unroll
    for (int i = 0; i < 8; ++i) {
        const int r = row0 + ty * 8 + i;
        float4 o;
        float* po = &o.x;
        #pragma unroll
        for (int j = 0; j < 4; ++j) {
            const float v = acc[i][j];
            po[j] = v / (1.f + __expf(-v));          // silu
        }
        *(float4*)&H1[(long)r * RH + col0 + tx * 4] = o;
    }
}

// ---------------- Kernel 3: logits = H1 @ W2^T, top-4, weights ----------------
__global__ __launch_bounds__(64) void router2_kernel(
    const float* __restrict__ H1, const float* __restrict__ W2,
    int* __restrict__ rid, float* __restrict__ rw) {
    __shared__ float w2s[RH][E + 1];
    const int tid = threadIdx.x;
    for (int i = tid; i < E * RH; i += 64) {
        const int e = i >> 8, h = i & 255;
        w2s[h][e] = W2[i];
    }
    __syncthreads();
    const int tok = blockIdx.x * 64 + tid;
    float l[E] = {};
    const float* hp = H1 + (long)tok * RH;
    for (int h = 0; h < RH; h += 4) {
        const float4 xv = *(const float4*)&hp[h];
        const float xs[4] = {xv.x, xv.y, xv.z, xv.w};
        #pragma unroll
        for (int q = 0; q < 4; ++q)
            #pragma unroll
            for (int e = 0; e < E; ++e)
                l[e] = fmaf(xs[q], w2s[h + q][e], l[e]);
    }
    unsigned chosen = 0u;
    float tv[4]; int ti[4];
    #pragma unroll
    for (int s = 0; s < 4; ++s) {
        float best = -1e30f; int bi = 0;
        #pragma unroll
        for (int e = 0; e < E; ++e) {
            const bool ok = (((chosen >> e) & 1u) == 0u) && (l[e] > best);
            best = ok ? l[e] : best;
            bi   = ok ? e    : bi;
        }
        chosen |= 1u << bi;
        tv[s] = best; ti[s] = bi;
    }
    const float m = tv[0];
    const float e0 = __expf(tv[0] - m), e1 = __expf(tv[1] - m);
    const float e2 = __expf(tv[2] - m), e3 = __expf(tv[3] - m);
    const float inv = 1.f / (e0 + e1 + e2 + e3);
    rid[tok * 4 + 0] = ti[0]; rw[tok * 4 + 0] = e0 * inv;
    rid[tok * 4 + 1] = ti[1]; rw[tok * 4 + 1] = e1 * inv;
    rid[tok * 4 + 2] = ti[2]; rw[tok * 4 + 2] = e2 * inv;
    rid[tok * 4 + 3] = ti[3]; rw[tok * 4 + 3] = e3 * inv;
}

// ---------------- Kernel 4: experts, fused zero-fill, single coalesced row write ----
__global__ __launch_bounds__(256) void expert_kernel(
    const float* __restrict__ X, const float* __restrict__ gT,
    const float* __restrict__ uT, const float* __restrict__ dT,
    const int* __restrict__ rid, const float* __restrict__ rw,
    float* __restrict__ out) {
    __shared__ float hids[4][H];
    __shared__ float row[C];           // full token output row (4 KB)
    const int tok  = blockIdx.x;
    const int tid  = threadIdx.x;
    // phase 0: zero the row (256 threads x float4 = 1024 floats)
    *(float4*)&row[tid * 4] = make_float4(0.f, 0.f, 0.f, 0.f);
    const int s    = tid >> 6;         // wave = top-k slot
    const int lane = tid & 63;
    const int e    = rid[tok * 4 + s];
    const float wt = rw[tok * 4 + s];
    const float* xb = X + (long)tok * C + e * D;
    float xv[D];
    #pragma unroll
    for (int d = 0; d < D; ++d) xv[d] = xb[d];       // wave-uniform broadcast loads
    const float* gp = gT + (e << 12);
    const float* up = uT + (e << 12);
    float g0 = 0.f, g1 = 0.f, u0 = 0.f, u1 = 0.f;
    #pragma unroll
    for (int d = 0; d < D; ++d) {                    // coalesced over h
        g0 = fmaf(xv[d], gp[d * H + lane],      g0);
        g1 = fmaf(xv[d], gp[d * H + 64 + lane], g1);
        u0 = fmaf(xv[d], up[d * H + lane],      u0);
        u1 = fmaf(xv[d], up[d * H + 64 + lane], u1);
    }
    hids[s][lane]      = g0 / (1.f + __expf(-g0)) * u0;
    hids[s][lane + 64] = g1 / (1.f + __expf(-g1)) * u1;
    __syncthreads();
    // phase 1: down-proj, write selected blocks into the row (top-4 distinct -> no clash)
    if (lane < D) {
        const float* dp = dT + (e << 12);
        float acc = 0.f;
        #pragma unroll
        for (int h = 0; h < H; ++h)                  // hids broadcast; dp coalesced
            acc = fmaf(hids[s][h], dp[h * D + lane], acc);
        row[e * D + lane] = wt * acc;
    }
    __syncthreads();
    // phase 2: single coalesced full-row write (covers the 28 zero blocks)
    *(float4*)&out[(long)tok * C + tid * 4] = *(const float4*)&row[tid * 4];
}

extern "C" void kernel_launch(void* const* d_in, const int* in_sizes, int n_in,
                              void* d_out, int out_size, void* d_ws, size_t ws_size,
                              hipStream_t stream) {
    const float* x  = (const float*)d_in[0];
    const float* w1 = (const float*)d_in[1];
    const float* w2 = (const float*)d_in[2];
    const float* gw = (const float*)d_in[3];
    const float* uw = (const float*)d_in[4];
    const float* dw = (const float*)d_in[5];
    float* out = (float*)d_out;

    char* ws = (char*)d_ws;
    float*  gT    = (float*)(ws);                                   // 512 KB
    float*  uT    = (float*)(ws + (512 << 10));                     // 512 KB
    float*  dT    = (float*)(ws + (1024 << 10));                    // 512 KB
    float*  H1    = (float*)(ws + (1536 << 10));                    // 16 MB
    int*    rid   = (int*)  (ws + (1536 << 10) + (16 << 20));       // 256 KB
    float*  rw    = (float*)(ws + (1536 << 10) + (16 << 20) + (256 << 10)); // 256 KB
    double* part  = (double*)(ws + (1536 << 10) + (16 << 20) + (512 << 10)); // 768 B
    float*  gamma = (float*) (ws + (1536 << 10) + (16 << 20) + (512 << 10) + 1024);

    absum_kernel<<<dim3(32, 3), 256, 0, stream>>>(gw, uw, dw, part);
    gamma_kernel<<<1, 64, 0, stream>>>(part, gamma);
    quant_t_kernel<<<3 * NEL / 256, 256, 0, stream>>>(gw, uw, dw, gamma, gT, uT, dT);
    dim3 g1(TOKENS / BM, RH / BN);
    gemm1_silu<<<g1, 256, 0, stream>>>(x, w1, H1);
    router2_kernel<<<TOKENS / 64, 64, 0, stream>>>(H1, w2, rid, rw);
    expert_kernel<<<TOKENS, 256, 0, stream>>>(x, gT, uT, dT, rid, rw, out);
}